// Round 5
// baseline (85.643 us; speedup 1.0000x reference)
//
#include <hip/hip_runtime.h>
#include <math.h>

#define BB 64
#define TT 2048
#define HIDD 256
#define FASTN 64
#define SLOWN 256
#define VOC 64
#define TLOOP (TT - 3)   // 2045 scan steps
#define NEGC -1000000000.0f
#define EPAD 257         // padded emb row stride (bank-conflict-free)
#define NEGBIG (-(1 << 20))
#define NW 16            // waves per block
#define NT (NW * 64)     // 1024 threads
#define ACTTH (-0.4054651081081644f)  // ln(2/3): sigmoid(x)>=0.4 <=> x>=ACTTH

// ---------------------------------------------------------------------------
// Single fused kernel (64 blocks x 1024 = 16 waves). vs previous version:
//  - bq/bo prefetched at kernel entry (were exposed ~900-cyc cold-HBM loads
//    mid-phase: the fills evict L2+L3 every iteration, so every mid-kernel
//    global load is HBM-cold)
//  - Wo prefetch issued one phase earlier (before the qp4 barrier)
//  - z-term expf(NEGC-m) dropped: == 0.0f exactly in f32 whenever any slot
//    is occupied (reference underflows identically); z==0 guarded
// Carried: fused staging+gate/dem dots w/ butterfly; per-wave rank; SWAR
// popcount composed Lindley maps; closed-form window eviction count;
// Wq register-pipelined GEMV (T14).
// ---------------------------------------------------------------------------

// popcount of x = (byte <= lane) over byte range [lo, hi) of zs; LL8 =
// (lane*0x01010101)|0x80808080. Requires all readable bytes <= 127.
__device__ __forceinline__ int countx(const unsigned char* zs, int lo, int hi,
                                      unsigned LL8) {
  int cnt = 0;
  for (int d = lo & ~3; d < hi; d += 4) {
    unsigned U = *(const unsigned*)(zs + d);
    unsigned m = (LL8 - U) & 0x80808080u;
    if (d < lo) m &= 0x80808080u << ((lo - d) << 3);
    if (d + 4 > hi) m &= 0x80808080u >> ((d + 4 - hi) << 3);
    cnt += __popc(m);
  }
  return cnt;
}

__global__ __launch_bounds__(NT) void k_one(
    const int* __restrict__ seq, const float* __restrict__ emb,
    const float* __restrict__ Wg, const float* __restrict__ bg,
    const float* __restrict__ Wd, const float* __restrict__ bd,
    const float* __restrict__ Wq, const float* __restrict__ bq,
    const float* __restrict__ Wo, const float* __restrict__ bo,
    float* __restrict__ out) {
  const int b = blockIdx.x;
  const int tid = threadIdx.x;
  const int lane = tid & 63;
  const int wv = tid >> 6;

  __shared__ float embS[VOC * EPAD];                    // 65792 B
  __shared__ __align__(16) unsigned char zsB[2080];
  __shared__ float qLastS[HIDD], ctxS[HIDD];
  __shared__ float pp16[NW][64];                        // scores/logits partials
  __shared__ float qp4[4][HIDD];                        // qLast partials
  __shared__ float demS[64], wS[64];
  __shared__ int prS[64], invS[64], cntTok[64];
  __shared__ int CS[NW];
  __shared__ int PsS[NW][64], QsS[NW][64], eSS[NW][64];

  // ---- entry: seq + all cold-HBM scalars/vectors issued up front ----
  const int2 sq = ((const int2*)(seq + b * TT))[tid];   // tokens 2t, 2t+1
  const int lastv = seq[b * TT + TT - 1];
  const int jq = tid & 255, kq = tid >> 8, kb = kq * 64;
  float wqA[32];
#pragma unroll
  for (int k = 0; k < 32; ++k) wqA[k] = Wq[(kb + k) * HIDD + jq];
  const float bqv = bq[jq];                             // used at qLast reduce
  const float bov = bo[lane];                           // used at final store
  const float4 Wg4 = ((const float4*)Wg)[lane];
  const float4 Wd4 = ((const float4*)Wd)[lane];
  const float bgv = bg[0];

  // ---- stage emb (padded) + fused gate/dem partial dots ----
  // thread covers rows wv+16c (c=0..3), cols 4*lane..4*lane+3
  float gc[4] = {0.f, 0.f, 0.f, 0.f}, dc[4] = {0.f, 0.f, 0.f, 0.f};
  const float4* emb4 = (const float4*)emb;
#pragma unroll
  for (int c2 = 0; c2 < 4; ++c2) {
    float4 e = emb4[c2 * 1024 + tid];
    float* dst = &embS[(wv + 16 * c2) * EPAD + (lane << 2)];
    dst[0] = e.x; dst[1] = e.y; dst[2] = e.z; dst[3] = e.w;
    gc[c2] += e.x * Wg4.x + e.y * Wg4.y + e.z * Wg4.z + e.w * Wg4.w;
    dc[c2] += e.x * Wd4.x + e.y * Wd4.y + e.z * Wd4.z + e.w * Wd4.w;
  }
  // butterfly all-reduce over 64 lanes (all lanes get identical sums)
#pragma unroll
  for (int off = 1; off < 64; off <<= 1) {
#pragma unroll
    for (int c2 = 0; c2 < 4; ++c2) {
      gc[c2] += __shfl_xor(gc[c2], off);
      dc[c2] += __shfl_xor(dc[c2], off);
    }
  }
  if (lane < 4) {
    float dv = lane == 0 ? dc[0] : lane == 1 ? dc[1] : lane == 2 ? dc[2] : dc[3];
    demS[wv + 16 * lane] = dv;
  }
  __syncthreads();

  // ---- rank: each wave ranks its own 4 rows (dem held in regs, all lanes) --
  {
    float du = demS[lane];
    int rc[4];
#pragma unroll
    for (int c2 = 0; c2 < 4; ++c2) {
      int v = wv + 16 * c2;
      rc[c2] = (du < dc[c2] || (du == dc[c2] && lane < v)) ? 1 : 0;
    }
#pragma unroll
    for (int off = 1; off < 64; off <<= 1) {
#pragma unroll
      for (int c2 = 0; c2 < 4; ++c2) rc[c2] += __shfl_xor(rc[c2], off);
    }
    if (lane < 4) {
      int rv = lane == 0 ? rc[0] : lane == 1 ? rc[1] : lane == 2 ? rc[2] : rc[3];
      float gv = lane == 0 ? gc[0] : lane == 1 ? gc[1] : lane == 2 ? gc[2] : gc[3];
      int v = wv + 16 * lane;
      int act = (gv + bgv >= ACTTH) ? 1 : 0;
      prS[v] = act ? rv : 0xFF;
      invS[rv] = v;
    }
  }
  __syncthreads();

  // ---- pack 2 tokens -> rank bytes; per-wave prefix; scatter to zsB ----
  const int t0 = tid * 2;
  int by0, by1, c;
  {
    int r0 = prS[sq.x], r1 = prS[sq.y];
    by0 = (t0 < TLOOP) ? r0 : 0xFF;
    by1 = (t0 + 1 < TLOOP) ? r1 : 0xFF;
    c = ((by0 != 0xFF) ? 1 : 0) + ((by1 != 0xFF) ? 1 : 0);
  }
  int incl = c;
  for (int s = 1; s < 64; s <<= 1) {
    int t = __shfl_up(incl, s);
    if (lane >= s) incl += t;
  }
  if (lane == 63) CS[wv] = incl;
  __syncthreads();

  int Ow = 0, A = 0;
#pragma unroll
  for (int w2 = 0; w2 < NW; ++w2) {
    int cw = CS[w2];
    Ow += (w2 < wv) ? cw : 0;
    A += cw;
  }
  {
    int pos = Ow + incl - c;
    if (by0 != 0xFF) zsB[pos++] = (unsigned char)by0;
    if (by1 != 0xFF) zsB[pos++] = (unsigned char)by1;
  }
  if (tid < 16) zsB[A + tid] = 0;   // SWAR-safe tail pad (reads < A+16)
  __syncthreads();

  const int fsplit = A < 64 ? A : 64;
  const int nL = A - fsplit;
  const int win = nL < 256 ? nL : 256;
  const int wstart = A - win;
  const int L = (((A + NW - 1) / NW) + 15) & ~15;  // seg len, mult of 16
  const int baseW = wv * L;
  const int endW = min(baseW + L, A);

  // slow_mask store, overlapped with the scan (independent of it)
  if (tid < 256)
    out[BB * VOC + b * SLOWN + tid] = (tid < win) ? 1.0f : 0.0f;

  // ---- pass 1: segment map (P,Q) via SWAR popcounts ----
  const unsigned LL8 = (unsigned)lane * 0x01010101u | 0x80808080u;
  const int fmin = min(endW, fsplit);          // end of FILL portion
  const int lf = max(baseW, fsplit);           // start of LRU portion
  const int wbl = max(lf, min(endW, wstart));  // start of window portion
  int cF = 0, cPre = 0, cWin = 0;
  if (fmin > baseW) cF = countx(zsB, baseW, fmin, LL8);
  if (wbl > lf) cPre = countx(zsB, lf, wbl, LL8);
  if (endW > wbl) cWin = countx(zsB, wbl, endW, LL8);
  const int lenL = endW - lf;
  {
    int P = cF + cPre + cWin - (lenL > 0 ? lenL : 0);
    int Q = (lenL > 0) ? ((zsB[endW - 1] <= lane) ? 1 : 0) : NEGBIG;
    PsS[wv][lane] = P;
    QsS[wv][lane] = Q;
  }
  // issue Wq half 2 now: lands under the barrier + wqA consume
  float wqB[32];
#pragma unroll
  for (int k = 0; k < 32; ++k) wqB[k] = Wq[(kb + 32 + k) * HIDD + jq];
  __syncthreads();

  // consume Wq half 1
  float qacc = 0.f;
  {
    const float* eL = &embS[lastv * EPAD + kb];
#pragma unroll
    for (int k = 0; k < 32; ++k) qacc += eL[k] * wqA[k];
  }

  // ---- pass 2 (window waves only): closed-form eviction count ----
  int e = 0;
  if (endW > wbl) {
    int a = 0;
    for (int w2 = 0; w2 < wv; ++w2)
      a = max(a + PsS[w2][lane], QsS[w2][lane]);
    a += cF;                                   // FILL portion: a -> a + cnt
    const int lenP = wbl - lf;                 // pre-window LRU portion
    if (lenP > 0) {
      int xl = (zsB[wbl - 1] <= lane) ? 1 : 0;
      a = max(a + cPre - lenP, xl);
    }
    const int n = endW - wbl;
    const int xw = (zsB[endW - 1] <= lane) ? 1 : 0;
    const int Zp = (n - cWin) - (1 - xw);      // zeros among first n-1 bytes
    const int F = max(0, Zp - a + 1);
    e = n - F;
  }
  eSS[wv][lane] = e;

  // consume Wq half 2
  {
    const float* eL = &embS[lastv * EPAD + kb + 32];
#pragma unroll
    for (int k = 0; k < 32; ++k) qacc += eL[k] * wqB[k];
  }

  // T14: issue Wo prefetch NOW (lands under finalize + scores + softmax)
  const int o = tid & 63, part = tid >> 6;
  float wor[16];
#pragma unroll
  for (int k = 0; k < 16; ++k) wor[k] = Wo[((part << 4) + k) * VOC + o];

  qp4[kq][jq] = qacc;
  __syncthreads();

  // ---- finalize (wave 4) parallel with qLast reduce (waves 0-3) ----
  if (wv == 4) {
    int af = 0;
#pragma unroll
    for (int w2 = 0; w2 < NW; ++w2)
      af = max(af + PsS[w2][lane], QsS[w2][lane]);
    int et = 0;
#pragma unroll
    for (int w2 = 0; w2 < NW; ++w2) et += eSS[w2][lane];
    int ap = __shfl_up(af, 1); if (lane == 0) ap = 0;
    int ep = __shfl_up(et, 1); if (lane == 0) ep = 0;
    cntTok[invS[lane]] = (af - ap) + (et - ep);
  }
  if (tid < 256)
    qLastS[tid] = qp4[0][tid] + qp4[1][tid] + qp4[2][tid] + qp4[3][tid] + bqv;
  __syncthreads();

  // ---- scores sc[v] = emb[v].qLast ; softmax regroup over counts ----
  {
    const float* er = &embS[o * EPAD + part * 16];
    const float* qr = &qLastS[part * 16];
    float s = 0.f;
#pragma unroll
    for (int k = 0; k < 16; ++k) s += er[k] * qr[k];
    pp16[part][o] = s;
  }
  __syncthreads();
  if (tid < 64) {
    float sc = 0.f;
#pragma unroll
    for (int p = 0; p < NW; ++p) sc += pp16[p][tid];
    int cc = cntTok[tid];
    float m = (cc > 0) ? sc : NEGC;
    for (int off = 32; off; off >>= 1) m = fmaxf(m, __shfl_xor(m, off));
    float w = (cc > 0) ? (float)cc * expf(sc - m) : 0.f;
    float z = w;
    for (int off = 32; off; off >>= 1) z += __shfl_xor(z, off);
    // masked-entry term expf(NEGC - m) == 0.0f exactly when m is finite
    // (reference underflows identically); guard the all-empty case only.
    if (z == 0.f) z = 1.f;
    wS[tid] = w / z;
  }
  __syncthreads();

  // ---- ctx[h] = sum_u wS[u] * emb[u][h]  (256 threads, direct) ----
  if (tid < 256) {
    float cacc = 0.f;
#pragma unroll 16
    for (int u = 0; u < 64; ++u) cacc += wS[u] * embS[u * EPAD + tid];
    ctxS[tid] = cacc;
  }
  __syncthreads();

  // ---- logits = ctx @ Wo + bo  (Wo already in registers) ----
  {
    const float* cr = &ctxS[part * 16];
    float s = 0.f;
#pragma unroll
    for (int k = 0; k < 16; ++k) s += cr[k] * wor[k];
    pp16[part][o] = s;
  }
  __syncthreads();
  if (tid < 64) {
    float s = bov;
#pragma unroll
    for (int p = 0; p < NW; ++p) s += pp16[p][tid];
    out[b * VOC + tid] = s;
  }
}

// ---------------------------------------------------------------------------
extern "C" void kernel_launch(void* const* d_in, const int* in_sizes, int n_in,
                              void* d_out, int out_size, void* d_ws, size_t ws_size,
                              hipStream_t stream) {
  const int*   seq = (const int*)d_in[0];
  const float* emb = (const float*)d_in[1];
  const float* Wg  = (const float*)d_in[2];
  const float* bg  = (const float*)d_in[3];
  const float* Wd  = (const float*)d_in[4];
  const float* bd  = (const float*)d_in[5];
  const float* Wq  = (const float*)d_in[6];
  const float* bq  = (const float*)d_in[7];
  const float* Wo  = (const float*)d_in[8];
  const float* bo  = (const float*)d_in[9];
  float* out = (float*)d_out;

  k_one<<<dim3(64), dim3(NT), 0, stream>>>(seq, emb, Wg, bg, Wd, bd,
                                           Wq, bq, Wo, bo, out);
}

// Round 6
// 83.700 us; speedup vs baseline: 1.0232x; 1.0232x over previous
//
#include <hip/hip_runtime.h>
#include <math.h>

#define BB 64
#define TT 2048
#define HIDD 256
#define FASTN 64
#define SLOWN 256
#define VOC 64
#define TLOOP (TT - 3)   // 2045 scan steps
#define NEGC -1000000000.0f
#define EPAD 257         // padded emb row stride (bank-conflict-free)
#define NEGBIG (-(1 << 20))
#define NW 16            // waves per block
#define NT (NW * 64)     // 1024 threads
#define ACTTH (-0.4054651081081644f)  // ln(2/3): sigmoid(x)>=0.4 <=> x>=ACTTH

// ---------------------------------------------------------------------------
// Single fused kernel (64 blocks x 1024 = 16 waves). R4 schedule (best
// measured: 84.8 us) + the two pressure-free R5 tweaks:
//  - bq/bo prefetched at entry (2 VGPRs; hides cold-HBM latency for free)
//  - z-term expf(NEGC-m) dropped (== 0.0f exactly when any slot occupied;
//    reference underflows identically); z==0 guarded
// REVERTED from R5: early Wo issue (16-VGPR live range across 2 barriers
// pushed past the 128-VGPR launch_bounds cap -> spills; Wo prefetch back to
// post-finalize position as in R4).
// Carried: fused staging+gate/dem dots w/ butterfly; per-wave rank; SWAR
// popcount composed Lindley maps; closed-form window eviction count;
// Wq register-pipelined GEMV (T14).
// ---------------------------------------------------------------------------

// popcount of x = (byte <= lane) over byte range [lo, hi) of zs; LL8 =
// (lane*0x01010101)|0x80808080. Requires all readable bytes <= 127.
__device__ __forceinline__ int countx(const unsigned char* zs, int lo, int hi,
                                      unsigned LL8) {
  int cnt = 0;
  for (int d = lo & ~3; d < hi; d += 4) {
    unsigned U = *(const unsigned*)(zs + d);
    unsigned m = (LL8 - U) & 0x80808080u;
    if (d < lo) m &= 0x80808080u << ((lo - d) << 3);
    if (d + 4 > hi) m &= 0x80808080u >> ((d + 4 - hi) << 3);
    cnt += __popc(m);
  }
  return cnt;
}

__global__ __launch_bounds__(NT) void k_one(
    const int* __restrict__ seq, const float* __restrict__ emb,
    const float* __restrict__ Wg, const float* __restrict__ bg,
    const float* __restrict__ Wd, const float* __restrict__ bd,
    const float* __restrict__ Wq, const float* __restrict__ bq,
    const float* __restrict__ Wo, const float* __restrict__ bo,
    float* __restrict__ out) {
  const int b = blockIdx.x;
  const int tid = threadIdx.x;
  const int lane = tid & 63;
  const int wv = tid >> 6;

  __shared__ float embS[VOC * EPAD];                    // 65792 B
  __shared__ __align__(16) unsigned char zsB[2080];
  __shared__ float qLastS[HIDD], ctxS[HIDD];
  __shared__ float pp16[NW][64];                        // scores/logits partials
  __shared__ float qp4[4][HIDD];                        // qLast partials
  __shared__ float demS[64], wS[64];
  __shared__ int prS[64], invS[64], cntTok[64];
  __shared__ int CS[NW];
  __shared__ int PsS[NW][64], QsS[NW][64], eSS[NW][64];

  // ---- entry: seq into regs; issue Wq half 1 + bq/bo (land under staging) --
  const int2 sq = ((const int2*)(seq + b * TT))[tid];   // tokens 2t, 2t+1
  const int lastv = seq[b * TT + TT - 1];
  const int jq = tid & 255, kq = tid >> 8, kb = kq * 64;
  float wqA[32];
#pragma unroll
  for (int k = 0; k < 32; ++k) wqA[k] = Wq[(kb + k) * HIDD + jq];
  const float bqv = bq[jq];                             // used at qLast reduce
  const float bov = bo[lane];                           // used at final store
  const float4 Wg4 = ((const float4*)Wg)[lane];
  const float4 Wd4 = ((const float4*)Wd)[lane];
  const float bgv = bg[0];

  // ---- stage emb (padded) + fused gate/dem partial dots ----
  // thread covers rows wv+16c (c=0..3), cols 4*lane..4*lane+3
  float gc[4] = {0.f, 0.f, 0.f, 0.f}, dc[4] = {0.f, 0.f, 0.f, 0.f};
  const float4* emb4 = (const float4*)emb;
#pragma unroll
  for (int c2 = 0; c2 < 4; ++c2) {
    float4 e = emb4[c2 * 1024 + tid];
    float* dst = &embS[(wv + 16 * c2) * EPAD + (lane << 2)];
    dst[0] = e.x; dst[1] = e.y; dst[2] = e.z; dst[3] = e.w;
    gc[c2] += e.x * Wg4.x + e.y * Wg4.y + e.z * Wg4.z + e.w * Wg4.w;
    dc[c2] += e.x * Wd4.x + e.y * Wd4.y + e.z * Wd4.z + e.w * Wd4.w;
  }
  // butterfly all-reduce over 64 lanes (all lanes get identical sums)
#pragma unroll
  for (int off = 1; off < 64; off <<= 1) {
#pragma unroll
    for (int c2 = 0; c2 < 4; ++c2) {
      gc[c2] += __shfl_xor(gc[c2], off);
      dc[c2] += __shfl_xor(dc[c2], off);
    }
  }
  if (lane < 4) {
    float dv = lane == 0 ? dc[0] : lane == 1 ? dc[1] : lane == 2 ? dc[2] : dc[3];
    demS[wv + 16 * lane] = dv;
  }
  __syncthreads();

  // ---- rank: each wave ranks its own 4 rows (dem held in regs, all lanes) --
  {
    float du = demS[lane];
    int rc[4];
#pragma unroll
    for (int c2 = 0; c2 < 4; ++c2) {
      int v = wv + 16 * c2;
      rc[c2] = (du < dc[c2] || (du == dc[c2] && lane < v)) ? 1 : 0;
    }
#pragma unroll
    for (int off = 1; off < 64; off <<= 1) {
#pragma unroll
      for (int c2 = 0; c2 < 4; ++c2) rc[c2] += __shfl_xor(rc[c2], off);
    }
    if (lane < 4) {
      int rv = lane == 0 ? rc[0] : lane == 1 ? rc[1] : lane == 2 ? rc[2] : rc[3];
      float gv = lane == 0 ? gc[0] : lane == 1 ? gc[1] : lane == 2 ? gc[2] : gc[3];
      int v = wv + 16 * lane;
      int act = (gv + bgv >= ACTTH) ? 1 : 0;
      prS[v] = act ? rv : 0xFF;
      invS[rv] = v;
    }
  }
  __syncthreads();

  // ---- pack 2 tokens -> rank bytes; per-wave prefix; scatter to zsB ----
  const int t0 = tid * 2;
  int by0, by1, c;
  {
    int r0 = prS[sq.x], r1 = prS[sq.y];
    by0 = (t0 < TLOOP) ? r0 : 0xFF;
    by1 = (t0 + 1 < TLOOP) ? r1 : 0xFF;
    c = ((by0 != 0xFF) ? 1 : 0) + ((by1 != 0xFF) ? 1 : 0);
  }
  int incl = c;
  for (int s = 1; s < 64; s <<= 1) {
    int t = __shfl_up(incl, s);
    if (lane >= s) incl += t;
  }
  if (lane == 63) CS[wv] = incl;
  __syncthreads();

  int Ow = 0, A = 0;
#pragma unroll
  for (int w2 = 0; w2 < NW; ++w2) {
    int cw = CS[w2];
    Ow += (w2 < wv) ? cw : 0;
    A += cw;
  }
  {
    int pos = Ow + incl - c;
    if (by0 != 0xFF) zsB[pos++] = (unsigned char)by0;
    if (by1 != 0xFF) zsB[pos++] = (unsigned char)by1;
  }
  if (tid < 16) zsB[A + tid] = 0;   // SWAR-safe tail pad (reads < A+16)
  __syncthreads();

  const int fsplit = A < 64 ? A : 64;
  const int nL = A - fsplit;
  const int win = nL < 256 ? nL : 256;
  const int wstart = A - win;
  const int L = (((A + NW - 1) / NW) + 15) & ~15;  // seg len, mult of 16
  const int baseW = wv * L;
  const int endW = min(baseW + L, A);

  // slow_mask store, overlapped with the scan (independent of it)
  if (tid < 256)
    out[BB * VOC + b * SLOWN + tid] = (tid < win) ? 1.0f : 0.0f;

  // ---- pass 1: segment map (P,Q) via SWAR popcounts ----
  const unsigned LL8 = (unsigned)lane * 0x01010101u | 0x80808080u;
  const int fmin = min(endW, fsplit);          // end of FILL portion
  const int lf = max(baseW, fsplit);           // start of LRU portion
  const int wbl = max(lf, min(endW, wstart));  // start of window portion
  int cF = 0, cPre = 0, cWin = 0;
  if (fmin > baseW) cF = countx(zsB, baseW, fmin, LL8);
  if (wbl > lf) cPre = countx(zsB, lf, wbl, LL8);
  if (endW > wbl) cWin = countx(zsB, wbl, endW, LL8);
  const int lenL = endW - lf;
  {
    int P = cF + cPre + cWin - (lenL > 0 ? lenL : 0);
    int Q = (lenL > 0) ? ((zsB[endW - 1] <= lane) ? 1 : 0) : NEGBIG;
    PsS[wv][lane] = P;
    QsS[wv][lane] = Q;
  }
  // issue Wq half 2 now: lands under the barrier + wqA consume
  float wqB[32];
#pragma unroll
  for (int k = 0; k < 32; ++k) wqB[k] = Wq[(kb + 32 + k) * HIDD + jq];
  __syncthreads();

  // consume Wq half 1
  float qacc = 0.f;
  {
    const float* eL = &embS[lastv * EPAD + kb];
#pragma unroll
    for (int k = 0; k < 32; ++k) qacc += eL[k] * wqA[k];
  }

  // ---- pass 2 (window waves only): closed-form eviction count ----
  int e = 0;
  if (endW > wbl) {
    int a = 0;
    for (int w2 = 0; w2 < wv; ++w2)
      a = max(a + PsS[w2][lane], QsS[w2][lane]);
    a += cF;                                   // FILL portion: a -> a + cnt
    const int lenP = wbl - lf;                 // pre-window LRU portion
    if (lenP > 0) {
      int xl = (zsB[wbl - 1] <= lane) ? 1 : 0;
      a = max(a + cPre - lenP, xl);
    }
    const int n = endW - wbl;
    const int xw = (zsB[endW - 1] <= lane) ? 1 : 0;
    const int Zp = (n - cWin) - (1 - xw);      // zeros among first n-1 bytes
    const int F = max(0, Zp - a + 1);
    e = n - F;
  }
  eSS[wv][lane] = e;

  // consume Wq half 2
  {
    const float* eL = &embS[lastv * EPAD + kb + 32];
#pragma unroll
    for (int k = 0; k < 32; ++k) qacc += eL[k] * wqB[k];
  }
  qp4[kq][jq] = qacc;
  __syncthreads();

  // ---- finalize (wave 4) parallel with qLast reduce (waves 0-3) ----
  if (wv == 4) {
    int af = 0;
#pragma unroll
    for (int w2 = 0; w2 < NW; ++w2)
      af = max(af + PsS[w2][lane], QsS[w2][lane]);
    int et = 0;
#pragma unroll
    for (int w2 = 0; w2 < NW; ++w2) et += eSS[w2][lane];
    int ap = __shfl_up(af, 1); if (lane == 0) ap = 0;
    int ep = __shfl_up(et, 1); if (lane == 0) ep = 0;
    cntTok[invS[lane]] = (af - ap) + (et - ep);
  }
  if (tid < 256)
    qLastS[tid] = qp4[0][tid] + qp4[1][tid] + qp4[2][tid] + qp4[3][tid] + bqv;
  __syncthreads();

  // T14: prefetch Wo rows for the logits phase (lands under scores/softmax/ctx)
  const int o = tid & 63, part = tid >> 6;
  float wor[16];
#pragma unroll
  for (int k = 0; k < 16; ++k) wor[k] = Wo[((part << 4) + k) * VOC + o];

  // ---- scores sc[v] = emb[v].qLast ; softmax regroup over counts ----
  {
    const float* er = &embS[o * EPAD + part * 16];
    const float* qr = &qLastS[part * 16];
    float s = 0.f;
#pragma unroll
    for (int k = 0; k < 16; ++k) s += er[k] * qr[k];
    pp16[part][o] = s;
  }
  __syncthreads();
  if (tid < 64) {
    float sc = 0.f;
#pragma unroll
    for (int p = 0; p < NW; ++p) sc += pp16[p][tid];
    int cc = cntTok[tid];
    float m = (cc > 0) ? sc : NEGC;
    for (int off = 32; off; off >>= 1) m = fmaxf(m, __shfl_xor(m, off));
    float w = (cc > 0) ? (float)cc * expf(sc - m) : 0.f;
    float z = w;
    for (int off = 32; off; off >>= 1) z += __shfl_xor(z, off);
    // masked-entry term expf(NEGC - m) == 0.0f exactly when m is finite
    // (reference underflows identically); guard the all-empty case only.
    if (z == 0.f) z = 1.f;
    wS[tid] = w / z;
  }
  __syncthreads();

  // ---- ctx[h] = sum_u wS[u] * emb[u][h]  (256 threads, direct) ----
  if (tid < 256) {
    float cacc = 0.f;
#pragma unroll 16
    for (int u = 0; u < 64; ++u) cacc += wS[u] * embS[u * EPAD + tid];
    ctxS[tid] = cacc;
  }
  __syncthreads();

  // ---- logits = ctx @ Wo + bo  (Wo already in registers) ----
  {
    const float* cr = &ctxS[part * 16];
    float s = 0.f;
#pragma unroll
    for (int k = 0; k < 16; ++k) s += cr[k] * wor[k];
    pp16[part][o] = s;
  }
  __syncthreads();
  if (tid < 64) {
    float s = bov;
#pragma unroll
    for (int p = 0; p < NW; ++p) s += pp16[p][tid];
    out[b * VOC + tid] = s;
  }
}

// ---------------------------------------------------------------------------
extern "C" void kernel_launch(void* const* d_in, const int* in_sizes, int n_in,
                              void* d_out, int out_size, void* d_ws, size_t ws_size,
                              hipStream_t stream) {
  const int*   seq = (const int*)d_in[0];
  const float* emb = (const float*)d_in[1];
  const float* Wg  = (const float*)d_in[2];
  const float* bg  = (const float*)d_in[3];
  const float* Wd  = (const float*)d_in[4];
  const float* bd  = (const float*)d_in[5];
  const float* Wq  = (const float*)d_in[6];
  const float* bq  = (const float*)d_in[7];
  const float* Wo  = (const float*)d_in[8];
  const float* bo  = (const float*)d_in[9];
  float* out = (float*)d_out;

  k_one<<<dim3(64), dim3(NT), 0, stream>>>(seq, emb, Wg, bg, Wd, bd,
                                           Wq, bq, Wo, bo, out);
}